// Round 5
// baseline (102.133 us; speedup 1.0000x reference)
//
#include <hip/hip_runtime.h>
#include <hip/hip_bf16.h>

#define N 2048
#define NL 1024
#define D 256

using bfrag = __attribute__((ext_vector_type(8))) short;   // 8 bf16
using ffrag = __attribute__((ext_vector_type(4))) float;   // 4 f32 acc

__device__ inline float bf2f(ushort u) {
    union { unsigned int i; float f; } x;
    x.i = ((unsigned int)u) << 16;
    return x.f;
}
__device__ inline ushort f2bf(float f) {
    return __builtin_bit_cast(unsigned short, __float2bfloat16(f));
}

// ws layout (bytes):
//   fB   [N*D]  ushort : [0, 1048576)
//   sq   [N]    f32    : [1048576, 1056768)
//   slab [NL]   f32    : [1056768, 1060864)
//   sidx [NL]   i32    : [1060864, 1064960)
//   rank [NL]   i32    : [1064960, 1069056)
//   bsum [256]  f32    : [1069056, 1070080)

__global__ __launch_bounds__(512) void k_prep3(
    const float* __restrict__ feat, const float* __restrict__ labels,
    ushort* __restrict__ fB, float* __restrict__ sq,
    float* __restrict__ slab, int* __restrict__ rank, int* __restrict__ sidx) {
    __shared__ float lab[NL];
    const int t = threadIdx.x;
    const int b = blockIdx.x;
    if (b >= 256) {
        // counting-rank sort of the 1024 labels (2 blocks x 512 thr)
        lab[t] = labels[t];
        lab[t + 512] = labels[t + 512];
        __syncthreads();
        const int j = (b - 256) * 512 + t;
        const float lj = lab[j];
        int r = 0;
#pragma unroll 4
        for (int k = 0; k < NL; ++k) {
            const float lk = lab[k];
            r += (lk < lj) ? 1 : ((lk == lj && k < j) ? 1 : 0);
        }
        slab[r] = lj;
        sidx[r] = j;
        rank[j] = r;
        return;
    }
    // bf16 convert + row square-norms: 8 rows per block, one per wave
    const int l = t & 63;
    const int row = b * 8 + (t >> 6);
    const float4 v = ((const float4*)(feat + (row & 1023) * 512 + (row >> 10) * 256))[l];
    float s = v.x * v.x + v.y * v.y + v.z * v.z + v.w * v.w;
#pragma unroll
    for (int off = 32; off; off >>= 1) s += __shfl_down(s, off);
    if (l == 0) sq[row] = s;
    ushort4 o;
    o.x = f2bf(v.x); o.y = f2bf(v.y); o.z = f2bf(v.z); o.w = f2bf(v.w);
    ((ushort4*)(fB + row * D))[l] = o;
}

__global__ __launch_bounds__(512) void k_fused(
    const ushort* __restrict__ fB, const float* __restrict__ sq,
    const float* __restrict__ slab, const int* __restrict__ sidx,
    const int* __restrict__ rank, const float* __restrict__ labels,
    float* __restrict__ bsum) {
    const int b = blockIdx.x;          // 256 blocks
    const int t = threadIdx.x;         // 512 = 8 waves
    const int l = t & 63, w = t >> 6;
    const int tile0 = (b >> 1) * 16;   // 16-row MFMA tile (pairs of blocks share)
    const int half = b & 1;            // which 8 rows this block keeps
    const int i0 = b * 8;              // global row base of kept rows

    __shared__ __align__(16) ushort erow[8][2048];  // bf16 e; later reused as f32 E[8][1024]
    __shared__ __align__(16) float slb[NL];
    __shared__ __align__(16) int sx[NL];
    __shared__ float red[8];

    ((float2*)slb)[t] = ((const float2*)slab)[t];
    ((int2*)sx)[t] = ((const int2*)sidx)[t];

    float contrib = 0.f;

    // ================= G phase: 16x2048 gram, keep 8 rows' e in LDS =================
    const int ko = (l >> 4) * 8;
    const ushort* arow = fB + (tile0 + (l & 15)) * D + ko;
    const int rg = l >> 4;

#pragma unroll
    for (int cp = 0; cp < 2; ++cp) {
        const int colbase = cp * 1024 + w * 128;
        const ushort* brow = fB + (colbase + (l & 15)) * D + ko;
        ffrag acc[8];
#pragma unroll
        for (int n = 0; n < 8; ++n) acc[n] = (ffrag){0.f, 0.f, 0.f, 0.f};
#pragma unroll
        for (int kk = 0; kk < 8; ++kk) {
            const bfrag a = *(const bfrag*)(arow + kk * 32);
#pragma unroll
            for (int n = 0; n < 8; ++n) {
                const bfrag bb = *(const bfrag*)(brow + n * 16 * D + kk * 32);
                acc[n] = __builtin_amdgcn_mfma_f32_16x16x32_bf16(a, bb, acc[n], 0, 0, 0);
            }
        }
        // epilogue: keep only this block's 8 rows
        if ((rg >> 1) == half) {
#pragma unroll
            for (int v = 0; v < 4; ++v) {
                const int gi = tile0 + rg * 4 + v;
                const int r = gi - i0;  // 0..7
                const float sqi = sq[gi];
#pragma unroll
                for (int n = 0; n < 8; ++n) {
                    const int gj = colbase + n * 16 + (l & 15);
                    const float d2 = sqi + sq[gj] - 2.f * acc[n][v];
                    const float lg = -0.5f * sqrtf(fmaxf(d2, 0.f));
                    const bool diag = (gj == gi);
                    const float e = diag ? 0.f : expf(lg);
                    if (!diag) contrib += lg;
                    erow[r][gj] = f2bf(e);
                }
            }
        }
    }
    __syncthreads();

    // ================= S phase: wave w owns row gi = i0 + w =================
    const int gi = i0 + w;
    const int oi = gi & 1023;
    const float labi = labels[oi];
    const int pc = rank[oi];

    // gather both views into label-sorted order; lane l owns p = 16l..16l+15
    int sxv[16];
    float val[16], pre[16];
    const ushort* er = &erow[w][0];
#pragma unroll
    for (int c = 0; c < 4; ++c) {
        const int4 s4 = ((const int4*)sx)[l * 4 + c];
        sxv[c * 4 + 0] = s4.x; sxv[c * 4 + 1] = s4.y;
        sxv[c * 4 + 2] = s4.z; sxv[c * 4 + 3] = s4.w;
        val[c * 4 + 0] = bf2f(er[s4.x]) + bf2f(er[s4.x + 1024]);
        val[c * 4 + 1] = bf2f(er[s4.y]) + bf2f(er[s4.y + 1024]);
        val[c * 4 + 2] = bf2f(er[s4.z]) + bf2f(er[s4.z + 1024]);
        val[c * 4 + 3] = bf2f(er[s4.w]) + bf2f(er[s4.w + 1024]);
    }
    float run = 0.f;
#pragma unroll
    for (int q = 0; q < 16; ++q) { pre[q] = run; run += val[q]; }
    float inc = run;
#pragma unroll
    for (int off = 1; off < 64; off <<= 1) {
        const float u = __shfl_up(inc, off);
        if (l >= off) inc += u;
    }
    const float tot = __shfl(inc, 63);
    const float base = inc - run;
    // overwrite this row's buffer with the f32 exclusive prefix (all gathers above
    // precede these writes in wave-ordered DS issue; wave owns the row exclusively)
    float* E = (float*)&erow[w][0];
#pragma unroll
    for (int c = 0; c < 4; ++c) {
        float4 o;
        o.x = base + pre[c * 4 + 0];
        o.y = base + pre[c * 4 + 1];
        o.z = base + pre[c * 4 + 2];
        o.w = base + pre[c * 4 + 3];
        ((float4*)&E[l * 16])[c] = o;
    }

    // branchless fixed-step searches on the V-shaped ld array (exact ld-space compares)
    const int lim = NL - pc;
#pragma unroll
    for (int q = 0; q < 16; ++q) {
        const int p = l * 16 + q;
        const float tq = fabsf(labi - slb[p]);
        int lo = 0;  // count of ld >= tq over left arm [0,pc)  -> ll
#pragma unroll
        for (int step = 512; step; step >>= 1) {
            const int cand = lo + step;
            const int ix = max(min(cand - 1, pc - 1), 0);
            const bool ok = (cand <= pc) && (fabsf(labi - slb[ix]) >= tq);
            lo = ok ? cand : lo;
        }
        int hi = 0;  // count of ld < tq over right arm [pc,NL) -> hl = pc + hi
#pragma unroll
        for (int step = 512; step; step >>= 1) {
            const int cand = hi + step;
            const int ix = min(pc + cand - 1, NL - 1);
            const bool ok = (cand <= lim) && (fabsf(labi - slb[ix]) < tq);
            hi = ok ? cand : hi;
        }
        const int hl = pc + hi;
        const float Eh = (hl == NL) ? tot : E[hl];
        const float dn = tot - (Eh - E[lo]);
        const float m2 = (sxv[q] == oi) ? 1.f : 2.f;
        contrib -= m2 * logf(dn);
    }

    // ================= block reduce =================
#pragma unroll
    for (int off = 32; off; off >>= 1) contrib += __shfl_xor(contrib, off);
    if (l == 0) red[w] = contrib;
    __syncthreads();
    if (t == 0) {
        float sb = 0.f;
#pragma unroll
        for (int q = 0; q < 8; ++q) sb += red[q];
        bsum[b] = sb;
    }
}

__global__ void k_final(const float* __restrict__ bs, float* __restrict__ out) {
    __shared__ double rd[4];
    const int t = threadIdx.x;  // 256
    double s = (double)bs[t];
#pragma unroll
    for (int off = 32; off; off >>= 1) s += __shfl_down(s, off);
    if ((t & 63) == 0) rd[t >> 6] = s;
    __syncthreads();
    if (t == 0) {
        const double tot = rd[0] + rd[1] + rd[2] + rd[3];
        out[0] = (float)(-tot / ((double)N * (double)(N - 1)));
    }
}

extern "C" void kernel_launch(void* const* d_in, const int* in_sizes, int n_in,
                              void* d_out, int out_size, void* d_ws, size_t ws_size,
                              hipStream_t stream) {
    const float* feat = (const float*)d_in[0];
    const float* labels = (const float*)d_in[1];
    char* ws = (char*)d_ws;
    ushort* fB = (ushort*)ws;
    float* sq = (float*)(ws + 1048576);
    float* slab = (float*)(ws + 1056768);
    int* sidx = (int*)(ws + 1060864);
    int* rank = (int*)(ws + 1064960);
    float* bsum = (float*)(ws + 1069056);

    k_prep3<<<258, 512, 0, stream>>>(feat, labels, fB, sq, slab, rank, sidx);
    k_fused<<<256, 512, 0, stream>>>(fB, sq, slab, sidx, rank, labels, bsum);
    k_final<<<1, 256, 0, stream>>>(bsum, (float*)d_out);
}

// Round 6
// 86.542 us; speedup vs baseline: 1.1802x; 1.1802x over previous
//
#include <hip/hip_runtime.h>
#include <hip/hip_bf16.h>

#define N 2048
#define NL 1024
#define D 256

using bfrag = __attribute__((ext_vector_type(8))) short;   // 8 bf16
using ffrag = __attribute__((ext_vector_type(4))) float;   // 4 f32 acc

__device__ inline float bf2f(ushort u) {
    union { unsigned int i; float f; } x;
    x.i = ((unsigned int)u) << 16;
    return x.f;
}
__device__ inline ushort f2bf(float f) {
    return __builtin_bit_cast(unsigned short, __float2bfloat16(f));
}

// ======== MAIN PATH ws layout (bytes), NEED = 13662208 ========
//   fB     [N*D]    ushort : 0
//   eG     [N*N]    ushort : 1048576
//   gidxG  [NL*NL]  ushort : 9437184
//   rstG   [NL*NL]  ushort : 11534336
//   sq     [N]      f32    : 13631488
//   slab   [NL]     f32    : 13639680
//   sidx   [NL]     i32    : 13643776
//   rank   [NL]     i32    : 13647872
//   bsg    [512]    f32    : 13651968
//   bss    [N]      f32    : 13654016   (end 13662208)

__global__ __launch_bounds__(512) void k_prep3(
    const float* __restrict__ feat, const float* __restrict__ labels,
    ushort* __restrict__ fB, float* __restrict__ sq,
    float* __restrict__ slab, int* __restrict__ rank, int* __restrict__ sidx) {
    __shared__ float lab[NL];
    const int t = threadIdx.x;
    const int b = blockIdx.x;
    if (b >= 256) {
        // counting-rank sort of the 1024 labels (2 blocks x 512 thr)
        lab[t] = labels[t];
        lab[t + 512] = labels[t + 512];
        __syncthreads();
        const int j = (b - 256) * 512 + t;
        const float lj = lab[j];
        int r = 0;
#pragma unroll 4
        for (int k = 0; k < NL; ++k) {
            const float lk = lab[k];
            r += (lk < lj) ? 1 : ((lk == lj && k < j) ? 1 : 0);
        }
        slab[r] = lj;
        sidx[r] = j;
        rank[j] = r;
        return;
    }
    // bf16 convert + row square-norms: 8 rows per block, one per wave
    const int l = t & 63;
    const int row = b * 8 + (t >> 6);
    const float4 v = ((const float4*)(feat + (row & 1023) * 512 + (row >> 10) * 256))[l];
    float s = v.x * v.x + v.y * v.y + v.z * v.z + v.w * v.w;
#pragma unroll
    for (int off = 32; off; off >>= 1) s += __shfl_down(s, off);
    if (l == 0) sq[row] = s;
    ushort4 o;
    o.x = f2bf(v.x); o.y = f2bf(v.y); o.z = f2bf(v.z); o.w = f2bf(v.w);
    ((ushort4*)(fB + row * D))[l] = o;
}

// G role (b<512): gram strip -> e (bf16) to eG, sum of lg -> bsg.
// T role (b>=512): per-label merge tables gidxG/rstG (8 oi per block).
__global__ __launch_bounds__(512) void k_GT(
    const ushort* __restrict__ fB, const float* __restrict__ sq,
    const float* __restrict__ slab, const int* __restrict__ sidx,
    const int* __restrict__ rank,
    ushort* __restrict__ eG, float* __restrict__ bsg,
    ushort* __restrict__ gidxG, ushort* __restrict__ rstG) {
    const int b = blockIdx.x;
    const int t = threadIdx.x;
    const int l = t & 63, w = t >> 6;

    if (b >= 512) {
        // ======================= T role =======================
        __shared__ float slb[NL];
        __shared__ int sx[NL];
        ((float2*)slb)[t] = ((const float2*)slab)[t];
        ((int2*)sx)[t] = ((const int2*)sidx)[t];
        __syncthreads();
        const int oi = (b - 512) * 8 + w;   // this wave's label
        const int pc = rank[oi];
        const float labi = slb[pc];
        const int nA = pc, nB = NL - pc;
        // arms (both weakly ascending, exact reference f32 values):
        //   A[a] = labi - slb[pc-1-a], a in [0,nA)   (left of pc)
        //   B[c] = slb[pc+c] - labi,   c in [0,nB)   (pc and right)
        const int d = 16 * l;  // this lane's merge-rank base
        // merge-path split (B first on ties)
        int alo = max(0, d - nB), ahi = min(d, nA);
        while (alo < ahi) {
            const int amid = (alo + ahi) >> 1;
            const float Av = labi - slb[pc - 1 - amid];
            const float Bv = slb[pc + (d - amid - 1)] - labi;
            if (Bv > Av) alo = amid + 1; else ahi = amid;
        }
        int a = alo, c = d - alo;
        int permp[16];
        float vals[16];
#pragma unroll
        for (int q = 0; q < 16; ++q) {
            const bool hasA = (a < nA), hasB = (c < nB);
            const float Av = hasA ? (labi - slb[pc - 1 - a]) : 0.f;
            const float Bv = hasB ? (slb[pc + c] - labi) : 0.f;
            const bool takeB = hasB && (!hasA || Bv <= Av);
            if (takeB) { permp[q] = pc + c;     vals[q] = Bv; ++c; }
            else       { permp[q] = pc - 1 - a; vals[q] = Av; ++a; }
        }
        // run starts: rstart[m] = index of first element with equal value
        const float pv0 = __shfl_up(vals[15], 1);  // lane l-1's last value
        int rs[16];
        int run = 0;
#pragma unroll
        for (int q = 0; q < 16; ++q) {
            const float pv = (q == 0) ? pv0 : vals[q - 1];
            const bool nr = (q == 0 && l == 0) ? false : (vals[q] != pv);
            if (nr) run = d + q;   // boundaries are increasing -> latest = max
            rs[q] = run;
        }
        int inc = run;
#pragma unroll
        for (int off = 1; off < 64; off <<= 1) {
            const int u = __shfl_up(inc, off);
            if (l >= off) inc = max(inc, u);
        }
        int excl = __shfl_up(inc, 1);
        if (l == 0) excl = 0;
        // pack + coalesced write (16 ushorts per lane, contiguous)
        unsigned gp[8], rp[8];
#pragma unroll
        for (int q = 0; q < 8; ++q) {
            const unsigned g0 = (unsigned)sx[permp[2 * q]];
            const unsigned g1 = (unsigned)sx[permp[2 * q + 1]];
            gp[q] = g0 | (g1 << 16);
            const unsigned r0 = (unsigned)max(rs[2 * q], excl);
            const unsigned r1 = (unsigned)max(rs[2 * q + 1], excl);
            rp[q] = r0 | (r1 << 16);
        }
        uint4* gdst = (uint4*)(gidxG + (size_t)oi * NL + d);
        uint4* rdst = (uint4*)(rstG + (size_t)oi * NL + d);
        gdst[0] = make_uint4(gp[0], gp[1], gp[2], gp[3]);
        gdst[1] = make_uint4(gp[4], gp[5], gp[6], gp[7]);
        rdst[0] = make_uint4(rp[0], rp[1], rp[2], rp[3]);
        rdst[1] = make_uint4(rp[4], rp[5], rp[6], rp[7]);
        return;
    }

    // ======================= G role =======================
    __shared__ float red[8];
    const int tile0 = (b >> 2) * 16;     // 16-row MFMA tile
    const int half = (b >> 1) & 1;       // which 8 rows this block keeps
    const int colbase = (b & 1) * 1024 + w * 128;  // this wave's 128 cols
    const int ko = (l >> 4) * 8;
    const ushort* arow = fB + (tile0 + (l & 15)) * D + ko;
    const ushort* brow = fB + (colbase + (l & 15)) * D + ko;
    ffrag acc[8];
#pragma unroll
    for (int n = 0; n < 8; ++n) acc[n] = (ffrag){0.f, 0.f, 0.f, 0.f};
#pragma unroll
    for (int kk = 0; kk < 8; ++kk) {
        const bfrag a = *(const bfrag*)(arow + kk * 32);
#pragma unroll
        for (int n = 0; n < 8; ++n) {
            const bfrag bb = *(const bfrag*)(brow + n * 16 * D + kk * 32);
            acc[n] = __builtin_amdgcn_mfma_f32_16x16x32_bf16(a, bb, acc[n], 0, 0, 0);
        }
    }
    float lgsum = 0.f;
    const int rg = l >> 4;
    if ((rg >> 1) == half) {
#pragma unroll
        for (int v = 0; v < 4; ++v) {
            const int gi = tile0 + rg * 4 + v;
            const float sqi = sq[gi];
#pragma unroll
            for (int n = 0; n < 8; ++n) {
                const int gj = colbase + n * 16 + (l & 15);
                const float d2 = sqi + sq[gj] - 2.f * acc[n][v];
                const float lg = -0.5f * sqrtf(fmaxf(d2, 0.f));
                const bool diag = (gj == gi);
                const float e = diag ? 0.f : expf(lg);
                if (!diag) lgsum += lg;
                eG[(size_t)gi * N + gj] = f2bf(e);
            }
        }
    }
#pragma unroll
    for (int off = 32; off; off >>= 1) lgsum += __shfl_xor(lgsum, off);
    if (l == 0) red[w] = lgsum;
    __syncthreads();
    if (t == 0) {
        float sb = 0.f;
#pragma unroll
        for (int q = 0; q < 8; ++q) sb += red[q];
        bsg[b] = sb;
    }
}

__global__ __launch_bounds__(256) void k_S2(
    const ushort* __restrict__ eG, const ushort* __restrict__ gidxG,
    const ushort* __restrict__ rstG, float* __restrict__ bss) {
    const int i = blockIdx.x;          // 2048 rows
    const int t = threadIdx.x;         // 256 = 4 waves
    const int l = t & 63, w = t >> 6;
    const int oi = i & 1023;

    __shared__ __align__(16) float ev[NL];      // summed views, original index
    __shared__ __align__(16) float E[NL + 8];   // exclusive prefix in merge order
    __shared__ float wpart[4];
    __shared__ float red[4];

    // load e row (both views) -> ev[j] = e[j] + e[j+1024]
    const ushort4 ea = ((const ushort4*)(eG + (size_t)i * N))[t];
    const ushort4 eb = ((const ushort4*)(eG + (size_t)i * N + 1024))[t];
    float4 evv;
    evv.x = bf2f(ea.x) + bf2f(eb.x);
    evv.y = bf2f(ea.y) + bf2f(eb.y);
    evv.z = bf2f(ea.z) + bf2f(eb.z);
    evv.w = bf2f(ea.w) + bf2f(eb.w);
    ((float4*)ev)[t] = evv;
    // tables: thread t owns merge ranks m = 4t..4t+3
    const ushort4 gx = ((const ushort4*)(gidxG + (size_t)oi * NL))[t];
    const ushort4 rs = ((const ushort4*)(rstG + (size_t)oi * NL))[t];
    __syncthreads();

    // gather into merge order
    float val[4];
    val[0] = ev[gx.x]; val[1] = ev[gx.y]; val[2] = ev[gx.z]; val[3] = ev[gx.w];
    float pre[4];
    float run = 0.f;
#pragma unroll
    for (int q = 0; q < 4; ++q) { pre[q] = run; run += val[q]; }
    float inc = run;
#pragma unroll
    for (int off = 1; off < 64; off <<= 1) {
        const float u = __shfl_up(inc, off);
        if (l >= off) inc += u;
    }
    if (l == 63) wpart[w] = inc;
    __syncthreads();
    float woff = 0.f;
#pragma unroll
    for (int q = 0; q < 4; ++q) woff += (q < w) ? wpart[q] : 0.f;
    const float base = woff + inc - run;
    {
        float4 o;
        o.x = base + pre[0]; o.y = base + pre[1];
        o.z = base + pre[2]; o.w = base + pre[3];
        ((float4*)E)[t] = o;
    }
    if (t == 255) E[NL] = base + run;
    __syncthreads();

    const float tot = E[NL];
    float contrib = 0.f;
    {
        const float dn0 = tot - E[rs.x];
        const float dn1 = tot - E[rs.y];
        const float dn2 = tot - E[rs.z];
        const float dn3 = tot - E[rs.w];
        contrib -= ((gx.x == oi) ? 1.f : 2.f) * logf(dn0);
        contrib -= ((gx.y == oi) ? 1.f : 2.f) * logf(dn1);
        contrib -= ((gx.z == oi) ? 1.f : 2.f) * logf(dn2);
        contrib -= ((gx.w == oi) ? 1.f : 2.f) * logf(dn3);
    }

#pragma unroll
    for (int off = 32; off; off >>= 1) contrib += __shfl_xor(contrib, off);
    if (l == 0) red[w] = contrib;
    __syncthreads();
    if (t == 0) bss[i] = red[0] + red[1] + red[2] + red[3];
}

__global__ void k_final3(const float* __restrict__ bsg, const float* __restrict__ bss,
                         float* __restrict__ out) {
    __shared__ double rd[4];
    const int t = threadIdx.x;  // 256
    double s = (double)bsg[t] + (double)bsg[t + 256];
#pragma unroll
    for (int r = 0; r < 8; ++r) s += (double)bss[t + 256 * r];
#pragma unroll
    for (int off = 32; off; off >>= 1) s += __shfl_down(s, off);
    if ((t & 63) == 0) rd[t >> 6] = s;
    __syncthreads();
    if (t == 0) {
        const double tot = rd[0] + rd[1] + rd[2] + rd[3];
        out[0] = (float)(-tot / ((double)N * (double)(N - 1)));
    }
}

// ================= FALLBACK PATH (round-5 fused, ~1.07 MB ws, proven) =================

__global__ __launch_bounds__(512) void k_fused(
    const ushort* __restrict__ fB, const float* __restrict__ sq,
    const float* __restrict__ slab, const int* __restrict__ sidx,
    const int* __restrict__ rank, const float* __restrict__ labels,
    float* __restrict__ bsum) {
    const int b = blockIdx.x;
    const int t = threadIdx.x;
    const int l = t & 63, w = t >> 6;
    const int tile0 = (b >> 1) * 16;
    const int half = b & 1;
    const int i0 = b * 8;

    __shared__ __align__(16) ushort erow[8][2048];
    __shared__ __align__(16) float slb[NL];
    __shared__ __align__(16) int sx[NL];
    __shared__ float red[8];

    ((float2*)slb)[t] = ((const float2*)slab)[t];
    ((int2*)sx)[t] = ((const int2*)sidx)[t];

    float contrib = 0.f;
    const int ko = (l >> 4) * 8;
    const ushort* arow = fB + (tile0 + (l & 15)) * D + ko;
    const int rg = l >> 4;

#pragma unroll
    for (int cp = 0; cp < 2; ++cp) {
        const int colbase = cp * 1024 + w * 128;
        const ushort* brow = fB + (colbase + (l & 15)) * D + ko;
        ffrag acc[8];
#pragma unroll
        for (int n = 0; n < 8; ++n) acc[n] = (ffrag){0.f, 0.f, 0.f, 0.f};
#pragma unroll
        for (int kk = 0; kk < 8; ++kk) {
            const bfrag a = *(const bfrag*)(arow + kk * 32);
#pragma unroll
            for (int n = 0; n < 8; ++n) {
                const bfrag bb = *(const bfrag*)(brow + n * 16 * D + kk * 32);
                acc[n] = __builtin_amdgcn_mfma_f32_16x16x32_bf16(a, bb, acc[n], 0, 0, 0);
            }
        }
        if ((rg >> 1) == half) {
#pragma unroll
            for (int v = 0; v < 4; ++v) {
                const int gi = tile0 + rg * 4 + v;
                const int r = gi - i0;
                const float sqi = sq[gi];
#pragma unroll
                for (int n = 0; n < 8; ++n) {
                    const int gj = colbase + n * 16 + (l & 15);
                    const float d2 = sqi + sq[gj] - 2.f * acc[n][v];
                    const float lg = -0.5f * sqrtf(fmaxf(d2, 0.f));
                    const bool diag = (gj == gi);
                    const float e = diag ? 0.f : expf(lg);
                    if (!diag) contrib += lg;
                    erow[r][gj] = f2bf(e);
                }
            }
        }
    }
    __syncthreads();

    const int gi = i0 + w;
    const int oi = gi & 1023;
    const float labi = labels[oi];
    const int pc = rank[oi];

    int sxv[16];
    float val[16], pre[16];
    const ushort* er = &erow[w][0];
#pragma unroll
    for (int c = 0; c < 4; ++c) {
        const int4 s4 = ((const int4*)sx)[l * 4 + c];
        sxv[c * 4 + 0] = s4.x; sxv[c * 4 + 1] = s4.y;
        sxv[c * 4 + 2] = s4.z; sxv[c * 4 + 3] = s4.w;
        val[c * 4 + 0] = bf2f(er[s4.x]) + bf2f(er[s4.x + 1024]);
        val[c * 4 + 1] = bf2f(er[s4.y]) + bf2f(er[s4.y + 1024]);
        val[c * 4 + 2] = bf2f(er[s4.z]) + bf2f(er[s4.z + 1024]);
        val[c * 4 + 3] = bf2f(er[s4.w]) + bf2f(er[s4.w + 1024]);
    }
    float run = 0.f;
#pragma unroll
    for (int q = 0; q < 16; ++q) { pre[q] = run; run += val[q]; }
    float inc = run;
#pragma unroll
    for (int off = 1; off < 64; off <<= 1) {
        const float u = __shfl_up(inc, off);
        if (l >= off) inc += u;
    }
    const float tot = __shfl(inc, 63);
    const float base = inc - run;
    float* E = (float*)&erow[w][0];
#pragma unroll
    for (int c = 0; c < 4; ++c) {
        float4 o;
        o.x = base + pre[c * 4 + 0];
        o.y = base + pre[c * 4 + 1];
        o.z = base + pre[c * 4 + 2];
        o.w = base + pre[c * 4 + 3];
        ((float4*)&E[l * 16])[c] = o;
    }

    const int lim = NL - pc;
#pragma unroll
    for (int q = 0; q < 16; ++q) {
        const int p = l * 16 + q;
        const float tq = fabsf(labi - slb[p]);
        int lo = 0;
#pragma unroll
        for (int step = 512; step; step >>= 1) {
            const int cand = lo + step;
            const int ix = max(min(cand - 1, pc - 1), 0);
            const bool ok = (cand <= pc) && (fabsf(labi - slb[ix]) >= tq);
            lo = ok ? cand : lo;
        }
        int hi = 0;
#pragma unroll
        for (int step = 512; step; step >>= 1) {
            const int cand = hi + step;
            const int ix = min(pc + cand - 1, NL - 1);
            const bool ok = (cand <= lim) && (fabsf(labi - slb[ix]) < tq);
            hi = ok ? cand : hi;
        }
        const int hl = pc + hi;
        const float Eh = (hl == NL) ? tot : E[hl];
        const float dn = tot - (Eh - E[lo]);
        const float m2 = (sxv[q] == oi) ? 1.f : 2.f;
        contrib -= m2 * logf(dn);
    }

#pragma unroll
    for (int off = 32; off; off >>= 1) contrib += __shfl_xor(contrib, off);
    if (l == 0) red[w] = contrib;
    __syncthreads();
    if (t == 0) {
        float sb = 0.f;
#pragma unroll
        for (int q = 0; q < 8; ++q) sb += red[q];
        bsum[b] = sb;
    }
}

__global__ void k_final_fb(const float* __restrict__ bs, float* __restrict__ out) {
    __shared__ double rd[4];
    const int t = threadIdx.x;
    double s = (double)bs[t];
#pragma unroll
    for (int off = 32; off; off >>= 1) s += __shfl_down(s, off);
    if ((t & 63) == 0) rd[t >> 6] = s;
    __syncthreads();
    if (t == 0) {
        const double tot = rd[0] + rd[1] + rd[2] + rd[3];
        out[0] = (float)(-tot / ((double)N * (double)(N - 1)));
    }
}

extern "C" void kernel_launch(void* const* d_in, const int* in_sizes, int n_in,
                              void* d_out, int out_size, void* d_ws, size_t ws_size,
                              hipStream_t stream) {
    const float* feat = (const float*)d_in[0];
    const float* labels = (const float*)d_in[1];
    char* ws = (char*)d_ws;

    if (ws_size >= 13662208ULL) {
        ushort* fB = (ushort*)ws;
        ushort* eG = (ushort*)(ws + 1048576);
        ushort* gidxG = (ushort*)(ws + 9437184);
        ushort* rstG = (ushort*)(ws + 11534336);
        float* sq = (float*)(ws + 13631488);
        float* slab = (float*)(ws + 13639680);
        int* sidx = (int*)(ws + 13643776);
        int* rank = (int*)(ws + 13647872);
        float* bsg = (float*)(ws + 13651968);
        float* bss = (float*)(ws + 13654016);

        k_prep3<<<258, 512, 0, stream>>>(feat, labels, fB, sq, slab, rank, sidx);
        k_GT<<<640, 512, 0, stream>>>(fB, sq, slab, sidx, rank, eG, bsg, gidxG, rstG);
        k_S2<<<2048, 256, 0, stream>>>(eG, gidxG, rstG, bss);
        k_final3<<<1, 256, 0, stream>>>(bsg, bss, (float*)d_out);
    } else {
        ushort* fB = (ushort*)ws;
        float* sq = (float*)(ws + 1048576);
        float* slab = (float*)(ws + 1056768);
        int* sidx = (int*)(ws + 1060864);
        int* rank = (int*)(ws + 1064960);
        float* bsum = (float*)(ws + 1069056);

        k_prep3<<<258, 512, 0, stream>>>(feat, labels, fB, sq, slab, rank, sidx);
        k_fused<<<256, 512, 0, stream>>>(fB, sq, slab, sidx, rank, labels, bsum);
        k_final_fb<<<1, 256, 0, stream>>>(bsum, (float*)d_out);
    }
}

// Round 7
// 68.177 us; speedup vs baseline: 1.4981x; 1.2694x over previous
//
#include <hip/hip_runtime.h>
#include <hip/hip_bf16.h>

#define N 2048
#define NL 1024
#define D 256

using bfrag = __attribute__((ext_vector_type(8))) short;   // 8 bf16
using ffrag = __attribute__((ext_vector_type(4))) float;   // 4 f32 acc

__device__ inline float bf2f(ushort u) {
    union { unsigned int i; float f; } x;
    x.i = ((unsigned int)u) << 16;
    return x.f;
}
__device__ inline ushort f2bf(float f) {
    return __builtin_bit_cast(unsigned short, __float2bfloat16(f));
}

// ======== MAIN PATH ws layout (bytes), NEED = 13662208 ========
//   fB     [N*D]    ushort : 0
//   eG     [N*N]    ushort : 1048576
//   gidxG  [NL*NL]  ushort : 9437184
//   rstG   [NL*NL]  ushort : 11534336
//   sq     [N]      f32    : 13631488
//   slab   [NL]     f32    : 13639680
//   sidx   [NL]     i32    : 13643776
//   rank   [NL]     i32    : 13647872
//   bsg    [512]    f32    : 13651968
//   bss    [N]      f32    : 13654016   (end 13662208)

__global__ __launch_bounds__(512) void k_prep3(
    const float* __restrict__ feat, const float* __restrict__ labels,
    ushort* __restrict__ fB, float* __restrict__ sq,
    float* __restrict__ slab, int* __restrict__ rank, int* __restrict__ sidx) {
    __shared__ float lab[NL];
    const int t = threadIdx.x;
    const int b = blockIdx.x;
    if (b < 2) {
        // counting-rank sort of the 1024 labels (first 2 blocks -> start early)
        lab[t] = labels[t];
        lab[t + 512] = labels[t + 512];
        __syncthreads();
        const int j = b * 512 + t;
        const float lj = lab[j];
        int r = 0;
#pragma unroll 4
        for (int k = 0; k < NL; ++k) {
            const float lk = lab[k];
            r += (lk < lj) ? 1 : ((lk == lj && k < j) ? 1 : 0);
        }
        slab[r] = lj;
        sidx[r] = j;
        rank[j] = r;
        return;
    }
    // bf16 convert + row square-norms: 8 rows per block, one per wave
    const int l = t & 63;
    const int row = (b - 2) * 8 + (t >> 6);
    const float4 v = ((const float4*)(feat + (row & 1023) * 512 + (row >> 10) * 256))[l];
    float s = v.x * v.x + v.y * v.y + v.z * v.z + v.w * v.w;
#pragma unroll
    for (int off = 32; off; off >>= 1) s += __shfl_down(s, off);
    if (l == 0) sq[row] = s;
    ushort4 o;
    o.x = f2bf(v.x); o.y = f2bf(v.y); o.z = f2bf(v.z); o.w = f2bf(v.w);
    ((ushort4*)(fB + row * D))[l] = o;
}

// b < 128 : T role — per-label merge tables gidxG/rstG (8 labels per block).
// b >= 128: G role — disjoint 16x512 gram strip -> e (bf16) to eG, sum lg -> bsg.
__global__ __launch_bounds__(512) void k_GT(
    const ushort* __restrict__ fB, const float* __restrict__ sq,
    const float* __restrict__ slab, const int* __restrict__ sidx,
    const int* __restrict__ rank,
    ushort* __restrict__ eG, float* __restrict__ bsg,
    ushort* __restrict__ gidxG, ushort* __restrict__ rstG) {
    const int b = blockIdx.x;
    const int t = threadIdx.x;
    const int l = t & 63, w = t >> 6;

    if (b < 128) {
        // ======================= T role (validated round 6) =======================
        __shared__ float slb[NL];
        __shared__ int sx[NL];
        ((float2*)slb)[t] = ((const float2*)slab)[t];
        ((int2*)sx)[t] = ((const int2*)sidx)[t];
        __syncthreads();
        const int oi = b * 8 + w;   // this wave's label
        const int pc = rank[oi];
        const float labi = slb[pc];
        const int nA = pc, nB = NL - pc;
        // arms (both weakly ascending, exact reference f32 values):
        //   A[a] = labi - slb[pc-1-a], a in [0,nA)   (left of pc)
        //   B[c] = slb[pc+c] - labi,   c in [0,nB)   (pc and right)
        const int d = 16 * l;  // this lane's merge-rank base
        // merge-path split (B first on ties)
        int alo = max(0, d - nB), ahi = min(d, nA);
        while (alo < ahi) {
            const int amid = (alo + ahi) >> 1;
            const float Av = labi - slb[pc - 1 - amid];
            const float Bv = slb[pc + (d - amid - 1)] - labi;
            if (Bv > Av) alo = amid + 1; else ahi = amid;
        }
        int a = alo, c = d - alo;
        int permp[16];
        float vals[16];
#pragma unroll
        for (int q = 0; q < 16; ++q) {
            const bool hasA = (a < nA), hasB = (c < nB);
            const float Av = hasA ? (labi - slb[pc - 1 - a]) : 0.f;
            const float Bv = hasB ? (slb[pc + c] - labi) : 0.f;
            const bool takeB = hasB && (!hasA || Bv <= Av);
            if (takeB) { permp[q] = pc + c;     vals[q] = Bv; ++c; }
            else       { permp[q] = pc - 1 - a; vals[q] = Av; ++a; }
        }
        // run starts: rstart[m] = index of first element with equal value
        const float pv0 = __shfl_up(vals[15], 1);  // lane l-1's last value
        int rs[16];
        int run = 0;
#pragma unroll
        for (int q = 0; q < 16; ++q) {
            const float pv = (q == 0) ? pv0 : vals[q - 1];
            const bool nr = (q == 0 && l == 0) ? false : (vals[q] != pv);
            if (nr) run = d + q;   // boundaries increasing -> latest = max
            rs[q] = run;
        }
        int inc = run;
#pragma unroll
        for (int off = 1; off < 64; off <<= 1) {
            const int u = __shfl_up(inc, off);
            if (l >= off) inc = max(inc, u);
        }
        int excl = __shfl_up(inc, 1);
        if (l == 0) excl = 0;
        // pack + coalesced write (16 ushorts per lane, contiguous)
        unsigned gp[8], rp[8];
#pragma unroll
        for (int q = 0; q < 8; ++q) {
            const unsigned g0 = (unsigned)sx[permp[2 * q]];
            const unsigned g1 = (unsigned)sx[permp[2 * q + 1]];
            gp[q] = g0 | (g1 << 16);
            const unsigned r0 = (unsigned)max(rs[2 * q], excl);
            const unsigned r1 = (unsigned)max(rs[2 * q + 1], excl);
            rp[q] = r0 | (r1 << 16);
        }
        uint4* gdst = (uint4*)(gidxG + (size_t)oi * NL + d);
        uint4* rdst = (uint4*)(rstG + (size_t)oi * NL + d);
        gdst[0] = make_uint4(gp[0], gp[1], gp[2], gp[3]);
        gdst[1] = make_uint4(gp[4], gp[5], gp[6], gp[7]);
        rdst[0] = make_uint4(rp[0], rp[1], rp[2], rp[3]);
        rdst[1] = make_uint4(rp[4], rp[5], rp[6], rp[7]);
        return;
    }

    // ======================= G role: disjoint 16x512 strip =======================
    __shared__ __align__(16) float sqs[N];   // 8 KB
    __shared__ float red[8];
    const int gb = b - 128;                  // 0..511
    const int tile0 = (gb >> 2) * 16;        // 128 row tiles
    const int colbase = (gb & 3) * 512 + w * 64;  // this wave's 64 cols

    ((float4*)sqs)[t] = ((const float4*)sq)[t];  // 512 x 4 = 2048 floats
    __syncthreads();

    const int ko = (l >> 4) * 8;
    const ushort* arow = fB + (tile0 + (l & 15)) * D + ko;
    const ushort* brow = fB + (colbase + (l & 15)) * D + ko;
    ffrag acc[4];
#pragma unroll
    for (int n = 0; n < 4; ++n) acc[n] = (ffrag){0.f, 0.f, 0.f, 0.f};
#pragma unroll
    for (int kk = 0; kk < 8; ++kk) {
        const bfrag a = *(const bfrag*)(arow + kk * 32);
#pragma unroll
        for (int n = 0; n < 4; ++n) {
            const bfrag bb = *(const bfrag*)(brow + n * 16 * D + kk * 32);
            acc[n] = __builtin_amdgcn_mfma_f32_16x16x32_bf16(a, bb, acc[n], 0, 0, 0);
        }
    }

    // epilogue: d2 -> lg -> e(bf16) -> eG; all sq from LDS
    const int rg = l >> 4;
    float sqi[4], sqj[4];
#pragma unroll
    for (int v = 0; v < 4; ++v) sqi[v] = sqs[tile0 + rg * 4 + v];
#pragma unroll
    for (int n = 0; n < 4; ++n) sqj[n] = sqs[colbase + n * 16 + (l & 15)];

    float lgsum = 0.f;
#pragma unroll
    for (int v = 0; v < 4; ++v) {
        const int gi = tile0 + rg * 4 + v;
#pragma unroll
        for (int n = 0; n < 4; ++n) {
            const int gj = colbase + n * 16 + (l & 15);
            const float d2 = sqi[v] + sqj[n] - 2.f * acc[n][v];
            const float lg = -0.5f * sqrtf(fmaxf(d2, 0.f));
            const bool diag = (gj == gi);
            const float e = diag ? 0.f : expf(lg);
            if (!diag) lgsum += lg;
            eG[(size_t)gi * N + gj] = f2bf(e);
        }
    }

#pragma unroll
    for (int off = 32; off; off >>= 1) lgsum += __shfl_xor(lgsum, off);
    if (l == 0) red[w] = lgsum;
    __syncthreads();
    if (t == 0) {
        float sb = 0.f;
#pragma unroll
        for (int q = 0; q < 8; ++q) sb += red[q];
        bsg[gb] = sb;
    }
}

// wave-per-row softmax-denominator: no __syncthreads (same-wave DS is in-order)
__global__ __launch_bounds__(256) void k_S3(
    const ushort* __restrict__ eG, const ushort* __restrict__ gidxG,
    const ushort* __restrict__ rstG, float* __restrict__ bss) {
    const int b = blockIdx.x;          // 512
    const int t = threadIdx.x;         // 256 = 4 waves
    const int l = t & 63, w = t >> 6;
    const int i = 2 * b + (w & 1) + (w >> 1) * 1024;  // rows 2b,2b+1,+1024 each
    const int oi = i & 1023;

    __shared__ __align__(16) float ev[4][NL];
    __shared__ __align__(16) float E[4][NL + 8];

    // load this row's e (both views): ev[j] = e[j] + e[j+1024], lane owns j=16l..16l+15
    const uint4* ep = (const uint4*)(eG + (size_t)i * N);  // 8 ushorts per uint4
    const uint4 e0 = ep[2 * l], e1 = ep[2 * l + 1];
    const uint4 f0 = ep[128 + 2 * l], f1 = ep[128 + 2 * l + 1];
    float evl[16];
#define UNPK(wrd, fwd, o)                                                   \
    evl[o]     = __uint_as_float((wrd) << 16) + __uint_as_float((fwd) << 16); \
    evl[o + 1] = __uint_as_float((wrd) & 0xffff0000u) +                      \
                 __uint_as_float((fwd) & 0xffff0000u);
    UNPK(e0.x, f0.x, 0)  UNPK(e0.y, f0.y, 2)  UNPK(e0.z, f0.z, 4)  UNPK(e0.w, f0.w, 6)
    UNPK(e1.x, f1.x, 8)  UNPK(e1.y, f1.y, 10) UNPK(e1.z, f1.z, 12) UNPK(e1.w, f1.w, 14)
#undef UNPK
#pragma unroll
    for (int c = 0; c < 4; ++c)
        ((float4*)&ev[w][l * 16])[c] =
            make_float4(evl[c * 4], evl[c * 4 + 1], evl[c * 4 + 2], evl[c * 4 + 3]);

    // merge tables for this label: lane owns merge ranks m = 16l..16l+15
    const uint4 g0 = ((const uint4*)(gidxG + (size_t)oi * NL))[2 * l];
    const uint4 g1 = ((const uint4*)(gidxG + (size_t)oi * NL))[2 * l + 1];
    const uint4 r0 = ((const uint4*)(rstG + (size_t)oi * NL))[2 * l];
    const uint4 r1 = ((const uint4*)(rstG + (size_t)oi * NL))[2 * l + 1];
    int gx[16], rs[16];
    {
        const unsigned gw[8] = {g0.x, g0.y, g0.z, g0.w, g1.x, g1.y, g1.z, g1.w};
        const unsigned rw[8] = {r0.x, r0.y, r0.z, r0.w, r1.x, r1.y, r1.z, r1.w};
#pragma unroll
        for (int q = 0; q < 8; ++q) {
            gx[2 * q] = gw[q] & 0xffff; gx[2 * q + 1] = gw[q] >> 16;
            rs[2 * q] = rw[q] & 0xffff; rs[2 * q + 1] = rw[q] >> 16;
        }
    }

    // gather in merge order (same-wave LDS, in-order), serial+wave prefix scan
    float val[16], pre[16];
#pragma unroll
    for (int q = 0; q < 16; ++q) val[q] = ev[w][gx[q]];
    float run = 0.f;
#pragma unroll
    for (int q = 0; q < 16; ++q) { pre[q] = run; run += val[q]; }
    float inc = run;
#pragma unroll
    for (int off = 1; off < 64; off <<= 1) {
        const float u = __shfl_up(inc, off);
        if (l >= off) inc += u;
    }
    const float tot = __shfl(inc, 63);
    const float base = inc - run;
#pragma unroll
    for (int c = 0; c < 4; ++c)
        ((float4*)&E[w][l * 16])[c] =
            make_float4(base + pre[c * 4], base + pre[c * 4 + 1],
                        base + pre[c * 4 + 2], base + pre[c * 4 + 3]);

    // denominators: dn = tot - E[rstart]
    float contrib = 0.f;
#pragma unroll
    for (int q = 0; q < 16; ++q) {
        const float dn = tot - E[w][rs[q]];
        const float m2 = (gx[q] == oi) ? 1.f : 2.f;
        contrib -= m2 * logf(dn);
    }

#pragma unroll
    for (int off = 32; off; off >>= 1) contrib += __shfl_xor(contrib, off);
    if (l == 0) bss[i] = contrib;
}

__global__ void k_final3(const float* __restrict__ bsg, const float* __restrict__ bss,
                         float* __restrict__ out) {
    __shared__ double rd[4];
    const int t = threadIdx.x;  // 256
    double s = (double)bsg[t] + (double)bsg[t + 256];
#pragma unroll
    for (int r = 0; r < 8; ++r) s += (double)bss[t + 256 * r];
#pragma unroll
    for (int off = 32; off; off >>= 1) s += __shfl_down(s, off);
    if ((t & 63) == 0) rd[t >> 6] = s;
    __syncthreads();
    if (t == 0) {
        const double tot = rd[0] + rd[1] + rd[2] + rd[3];
        out[0] = (float)(-tot / ((double)N * (double)(N - 1)));
    }
}

// ================= FALLBACK PATH (round-5 fused, ~1.07 MB ws, proven) =================

__global__ __launch_bounds__(512) void k_fused(
    const ushort* __restrict__ fB, const float* __restrict__ sq,
    const float* __restrict__ slab, const int* __restrict__ sidx,
    const int* __restrict__ rank, const float* __restrict__ labels,
    float* __restrict__ bsum) {
    const int b = blockIdx.x;
    const int t = threadIdx.x;
    const int l = t & 63, w = t >> 6;
    const int tile0 = (b >> 1) * 16;
    const int half = b & 1;
    const int i0 = b * 8;

    __shared__ __align__(16) ushort erow[8][2048];
    __shared__ __align__(16) float slb[NL];
    __shared__ __align__(16) int sx[NL];
    __shared__ float red[8];

    ((float2*)slb)[t] = ((const float2*)slab)[t];
    ((int2*)sx)[t] = ((const int2*)sidx)[t];

    float contrib = 0.f;
    const int ko = (l >> 4) * 8;
    const ushort* arow = fB + (tile0 + (l & 15)) * D + ko;
    const int rg = l >> 4;

#pragma unroll
    for (int cp = 0; cp < 2; ++cp) {
        const int colbase = cp * 1024 + w * 128;
        const ushort* brow = fB + (colbase + (l & 15)) * D + ko;
        ffrag acc[8];
#pragma unroll
        for (int n = 0; n < 8; ++n) acc[n] = (ffrag){0.f, 0.f, 0.f, 0.f};
#pragma unroll
        for (int kk = 0; kk < 8; ++kk) {
            const bfrag a = *(const bfrag*)(arow + kk * 32);
#pragma unroll
            for (int n = 0; n < 8; ++n) {
                const bfrag bb = *(const bfrag*)(brow + n * 16 * D + kk * 32);
                acc[n] = __builtin_amdgcn_mfma_f32_16x16x32_bf16(a, bb, acc[n], 0, 0, 0);
            }
        }
        if ((rg >> 1) == half) {
#pragma unroll
            for (int v = 0; v < 4; ++v) {
                const int gi = tile0 + rg * 4 + v;
                const int r = gi - i0;
                const float sqi = sq[gi];
#pragma unroll
                for (int n = 0; n < 8; ++n) {
                    const int gj = colbase + n * 16 + (l & 15);
                    const float d2 = sqi + sq[gj] - 2.f * acc[n][v];
                    const float lg = -0.5f * sqrtf(fmaxf(d2, 0.f));
                    const bool diag = (gj == gi);
                    const float e = diag ? 0.f : expf(lg);
                    if (!diag) contrib += lg;
                    erow[r][gj] = f2bf(e);
                }
            }
        }
    }
    __syncthreads();

    const int gi = i0 + w;
    const int oi = gi & 1023;
    const float labi = labels[oi];
    const int pc = rank[oi];

    int sxv[16];
    float val[16], pre[16];
    const ushort* er = &erow[w][0];
#pragma unroll
    for (int c = 0; c < 4; ++c) {
        const int4 s4 = ((const int4*)sx)[l * 4 + c];
        sxv[c * 4 + 0] = s4.x; sxv[c * 4 + 1] = s4.y;
        sxv[c * 4 + 2] = s4.z; sxv[c * 4 + 3] = s4.w;
        val[c * 4 + 0] = bf2f(er[s4.x]) + bf2f(er[s4.x + 1024]);
        val[c * 4 + 1] = bf2f(er[s4.y]) + bf2f(er[s4.y + 1024]);
        val[c * 4 + 2] = bf2f(er[s4.z]) + bf2f(er[s4.z + 1024]);
        val[c * 4 + 3] = bf2f(er[s4.w]) + bf2f(er[s4.w + 1024]);
    }
    float run = 0.f;
#pragma unroll
    for (int q = 0; q < 16; ++q) { pre[q] = run; run += val[q]; }
    float inc = run;
#pragma unroll
    for (int off = 1; off < 64; off <<= 1) {
        const float u = __shfl_up(inc, off);
        if (l >= off) inc += u;
    }
    const float tot = __shfl(inc, 63);
    const float base = inc - run;
    float* E = (float*)&erow[w][0];
#pragma unroll
    for (int c = 0; c < 4; ++c) {
        float4 o;
        o.x = base + pre[c * 4 + 0];
        o.y = base + pre[c * 4 + 1];
        o.z = base + pre[c * 4 + 2];
        o.w = base + pre[c * 4 + 3];
        ((float4*)&E[l * 16])[c] = o;
    }

    const int lim = NL - pc;
#pragma unroll
    for (int q = 0; q < 16; ++q) {
        const int p = l * 16 + q;
        const float tq = fabsf(labi - slb[p]);
        int lo = 0;
#pragma unroll
        for (int step = 512; step; step >>= 1) {
            const int cand = lo + step;
            const int ix = max(min(cand - 1, pc - 1), 0);
            const bool ok = (cand <= pc) && (fabsf(labi - slb[ix]) >= tq);
            lo = ok ? cand : lo;
        }
        int hi = 0;
#pragma unroll
        for (int step = 512; step; step >>= 1) {
            const int cand = hi + step;
            const int ix = min(pc + cand - 1, NL - 1);
            const bool ok = (cand <= lim) && (fabsf(labi - slb[ix]) < tq);
            hi = ok ? cand : hi;
        }
        const int hl = pc + hi;
        const float Eh = (hl == NL) ? tot : E[hl];
        const float dn = tot - (Eh - E[lo]);
        const float m2 = (sxv[q] == oi) ? 1.f : 2.f;
        contrib -= m2 * logf(dn);
    }

#pragma unroll
    for (int off = 32; off; off >>= 1) contrib += __shfl_xor(contrib, off);
    if (l == 0) red[w] = contrib;
    __syncthreads();
    if (t == 0) {
        float sb = 0.f;
#pragma unroll
        for (int q = 0; q < 8; ++q) sb += red[q];
        bsum[b] = sb;
    }
}

__global__ void k_final_fb(const float* __restrict__ bs, float* __restrict__ out) {
    __shared__ double rd[4];
    const int t = threadIdx.x;
    double s = (double)bs[t];
#pragma unroll
    for (int off = 32; off; off >>= 1) s += __shfl_down(s, off);
    if ((t & 63) == 0) rd[t >> 6] = s;
    __syncthreads();
    if (t == 0) {
        const double tot = rd[0] + rd[1] + rd[2] + rd[3];
        out[0] = (float)(-tot / ((double)N * (double)(N - 1)));
    }
}

extern "C" void kernel_launch(void* const* d_in, const int* in_sizes, int n_in,
                              void* d_out, int out_size, void* d_ws, size_t ws_size,
                              hipStream_t stream) {
    const float* feat = (const float*)d_in[0];
    const float* labels = (const float*)d_in[1];
    char* ws = (char*)d_ws;

    if (ws_size >= 13662208ULL) {
        ushort* fB = (ushort*)ws;
        ushort* eG = (ushort*)(ws + 1048576);
        ushort* gidxG = (ushort*)(ws + 9437184);
        ushort* rstG = (ushort*)(ws + 11534336);
        float* sq = (float*)(ws + 13631488);
        float* slab = (float*)(ws + 13639680);
        int* sidx = (int*)(ws + 13643776);
        int* rank = (int*)(ws + 13647872);
        float* bsg = (float*)(ws + 13651968);
        float* bss = (float*)(ws + 13654016);

        k_prep3<<<258, 512, 0, stream>>>(feat, labels, fB, sq, slab, rank, sidx);
        k_GT<<<640, 512, 0, stream>>>(fB, sq, slab, sidx, rank, eG, bsg, gidxG, rstG);
        k_S3<<<512, 256, 0, stream>>>(eG, gidxG, rstG, bss);
        k_final3<<<1, 256, 0, stream>>>(bsg, bss, (float*)d_out);
    } else {
        ushort* fB = (ushort*)ws;
        float* sq = (float*)(ws + 1048576);
        float* slab = (float*)(ws + 1056768);
        int* sidx = (int*)(ws + 1060864);
        int* rank = (int*)(ws + 1064960);
        float* bsum = (float*)(ws + 1069056);

        k_prep3<<<258, 512, 0, stream>>>(feat, labels, fB, sq, slab, rank, sidx);
        k_fused<<<256, 512, 0, stream>>>(fB, sq, slab, sidx, rank, labels, bsum);
        k_final_fb<<<1, 256, 0, stream>>>(bsum, (float*)d_out);
    }
}